// Round 2
// baseline (354.547 us; speedup 1.0000x reference)
//
#include <hip/hip_runtime.h>

#define N_NODES 6144
#define ATTD 128
#define HIDD 96
#define EPT 100000
#define NTYPE 3
#define NEDGE (NTYPE * EPT)
#define HBITS 19
#define HSIZE (1u << HBITS)
#define HMASK (HSIZE - 1)
#define NEG 0.2f

// ---------------- params: per (l,h): {w0, w_last, es0, es1, es2}; zero stot/ecount ----
__global__ void k_params(const float* __restrict__ attn_w,
                         const float* __restrict__ edge_emb,
                         float* __restrict__ params, float* __restrict__ stot,
                         int* __restrict__ ecount) {
    int i = threadIdx.x;
    if (i < 2) stot[i] = 0.f;
    if (i == 0) *ecount = 0;
    if (i < 4) {
        // attn_w flat: (2,2,22,1) -> (l*2+h)*22 + j
        const float* w = attn_w + i * 22;
        float* p = params + i * 8;
        p[0] = w[0];    // w0 (src coeff)
        p[1] = w[21];   // w_last (tgt coeff)
        for (int t = 0; t < NTYPE; ++t) {
            float acc = 0.f;
            for (int j = 0; j < 20; ++j) acc += edge_emb[t * 20 + j] * w[1 + j];
            p[2 + t] = acc;
        }
    }
}

// ---------------- hash init + zero degrees ----------------
__global__ void k_hash_init(int* __restrict__ hkey, int* __restrict__ hcnt,
                            int* __restrict__ deg) {
    int i = blockIdx.x * blockDim.x + threadIdx.x;
    if (i < (int)HSIZE) { hkey[i] = -1; hcnt[i] = 0; }
    if (i <= N_NODES) deg[i] = 0;
}

// ---------------- insert edges, dedupe by (src,tgt), count per type ----------------
__global__ void k_insert(const int* __restrict__ edges,
                         int* __restrict__ hkey, int* __restrict__ hcnt) {
    int k = blockIdx.x * blockDim.x + threadIdx.x;
    if (k >= NEDGE) return;
    int t = k / EPT;
    int e = k - t * EPT;
    int src = edges[t * (2 * EPT) + e];
    int tgt = edges[t * (2 * EPT) + EPT + e];
    int key = (src << 13) | tgt;   // both < 8192
    unsigned slot = ((unsigned)key * 2654435761u) >> (32 - HBITS);
    while (true) {
        int prev = atomicCAS(&hkey[slot], -1, key);
        if (prev == -1 || prev == key) break;
        slot = (slot + 1) & HMASK;
    }
    atomicAdd(&hcnt[slot], 1 << (10 * t));  // packed 3x10-bit type counts
}

// ---------------- MLP scores: s = leaky(X@W1+b1)@W2 + b2; fused stot[0] ----------------
__global__ void k_mlp(const float* __restrict__ X, const float* __restrict__ W1,
                      const float* __restrict__ b1, const float* __restrict__ W2,
                      const float* __restrict__ b2, float* __restrict__ s,
                      float* __restrict__ stot) {
    int row = blockIdx.x;
    int tid = threadIdx.x;
    __shared__ float xs[ATTD];
    xs[tid] = X[row * ATTD + tid];
    __syncthreads();
    float val = 0.f;
    if (tid < HIDD) {
        float acc = b1[tid];
#pragma unroll
        for (int k = 0; k < ATTD; ++k) acc += xs[k] * W1[k * HIDD + tid];
        float h = acc > 0.f ? acc : NEG * acc;
        val = h * W2[tid];
    }
#pragma unroll
    for (int off = 32; off; off >>= 1) val += __shfl_down(val, off, 64);
    __shared__ float red[2];
    if ((tid & 63) == 0) red[tid >> 6] = val;
    __syncthreads();
    if (tid == 0) {
        float r = red[0] + red[1] + b2[0];
        s[row] = r;
        atomicAdd(&stot[0], r);
    }
}

// ---------------- compact hash -> dense entry list + per-row degree count -------------
__global__ void k_compact(const int* __restrict__ hkey, const int* __restrict__ hcnt,
                          int* __restrict__ elist_k, int* __restrict__ elist_c,
                          int* __restrict__ deg, int* __restrict__ ecount) {
    int i = blockIdx.x * blockDim.x + threadIdx.x;
    if (i >= (int)HSIZE) return;
    int key = hkey[i];
    if (key < 0) return;
    int idx = atomicAdd(ecount, 1);
    elist_k[idx] = key;
    elist_c[idx] = hcnt[i];
    atomicAdd(&deg[key >> 13], 1);
}

// ---------------- single-block exclusive scan of degrees -> rowptr, rowcur ------------
__global__ void k_scan(const int* __restrict__ deg, int* __restrict__ rowptr,
                       int* __restrict__ rowcur) {
    __shared__ int part[1024];
    int t = threadIdx.x;
    int base = t * 6;           // 6144 / 1024
    int d[6];
    int sum = 0;
#pragma unroll
    for (int j = 0; j < 6; ++j) { d[j] = deg[base + j]; sum += d[j]; }
    part[t] = sum;
    __syncthreads();
    for (int off = 1; off < 1024; off <<= 1) {
        int v = (t >= off) ? part[t - off] : 0;
        __syncthreads();
        part[t] += v;
        __syncthreads();
    }
    int run = part[t] - sum;    // exclusive prefix of this thread
#pragma unroll
    for (int j = 0; j < 6; ++j) {
        rowptr[base + j] = run;
        rowcur[base + j] = run;
        run += d[j];
    }
    if (t == 1023) rowptr[N_NODES] = run;
}

// ---------------- scatter entries into CSR order ----------------
__global__ void k_scatter(const int* __restrict__ elist_k, const int* __restrict__ elist_c,
                          const int* __restrict__ ecount, int* __restrict__ rowcur,
                          int* __restrict__ csr_v, int* __restrict__ csr_c) {
    int i = blockIdx.x * blockDim.x + threadIdx.x;
    if (i >= *ecount) return;
    int key = elist_k[i];
    int u = key >> 13;
    int pos = atomicAdd(&rowcur[u], 1);
    csr_v[pos] = key & 8191;
    csr_c[pos] = elist_c[i];
}

// ---------------- per-layer gather: one wave per row, no atomics in hot path ----------
__global__ void k_gather(const int* __restrict__ rowptr, const int* __restrict__ csr_v,
                         const int* __restrict__ csr_c, const float* __restrict__ s,
                         const float* __restrict__ params, const float* __restrict__ stot_l,
                         float* __restrict__ dst, float* __restrict__ stot_next, int l) {
    int wid = (blockIdx.x * blockDim.x + threadIdx.x) >> 6;
    int lane = threadIdx.x & 63;
    if (wid >= N_NODES) return;
    int u = wid;
    float su = s[u];
    const float* p0 = params + (l * 2 + 0) * 8;
    const float* p1 = params + (l * 2 + 1) * 8;
    float w00 = p0[0], w01 = p0[1], e00 = p0[2], e01 = p0[3], e02 = p0[4];
    float w10 = p1[0], w11 = p1[1], e10 = p1[2], e11 = p1[3], e12 = p1[4];
    float num0 = 0.f, den0 = 0.f, num1 = 0.f, den1 = 0.f;
    int beg = rowptr[u], end = rowptr[u + 1];
    for (int i = beg + lane; i < end; i += 64) {
        int v = csr_v[i];
        int cw = csr_c[i];
        float c0 = (float)(cw & 1023);
        float c1 = (float)((cw >> 10) & 1023);
        float c2 = (float)((cw >> 20) & 1023);
        float C = c0 + c1 + c2;
        float sv = s[v];
        float A0 = C * (w00 * su + w01 * sv) + c0 * e00 + c1 * e01 + c2 * e02;
        float la0 = A0 > 0.f ? A0 : NEG * A0;
        float g0 = expf(la0) - 1.f;
        num0 += g0 * sv; den0 += g0;
        float A1 = C * (w10 * su + w11 * sv) + c0 * e10 + c1 * e11 + c2 * e12;
        float la1 = A1 > 0.f ? A1 : NEG * A1;
        float g1 = expf(la1) - 1.f;
        num1 += g1 * sv; den1 += g1;
    }
#pragma unroll
    for (int off = 32; off; off >>= 1) {
        num0 += __shfl_down(num0, off, 64);
        den0 += __shfl_down(den0, off, 64);
        num1 += __shfl_down(num1, off, 64);
        den1 += __shfl_down(den1, off, 64);
    }
    if (lane == 0) {
        float S = *stot_l;
        float r0 = (S + num0) / ((float)N_NODES + den0);
        float r1 = (S + num1) / ((float)N_NODES + den1);
        float val = 0.5f * (r0 + r1);
        dst[u] = val;
        if (stot_next) atomicAdd(stot_next, val);
    }
}

extern "C" void kernel_launch(void* const* d_in, const int* in_sizes, int n_in,
                              void* d_out, int out_size, void* d_ws, size_t ws_size,
                              hipStream_t stream) {
    const float* X        = (const float*)d_in[0];
    const int*   edges    = (const int*)d_in[1];
    const float* W1       = (const float*)d_in[2];
    const float* b1       = (const float*)d_in[3];
    const float* W2       = (const float*)d_in[4];
    const float* b2       = (const float*)d_in[5];
    const float* edge_emb = (const float*)d_in[6];
    const float* attn_w   = (const float*)d_in[7];
    float* out = (float*)d_out;

    char* w = (char*)d_ws;
    float* params  = (float*)w; w += 256;
    float* stot    = (float*)w; w += 256;
    int*   ecount  = (int*)w;   w += 256;
    float* s       = (float*)w; w += N_NODES * sizeof(float);
    float* s2      = (float*)w; w += N_NODES * sizeof(float);
    int*   deg     = (int*)w;   w += (N_NODES + 64) * sizeof(int);
    int*   rowptr  = (int*)w;   w += (N_NODES + 64) * sizeof(int);
    int*   rowcur  = (int*)w;   w += (N_NODES + 64) * sizeof(int);
    int*   elist_k = (int*)w;   w += NEDGE * sizeof(int);
    int*   elist_c = (int*)w;   w += NEDGE * sizeof(int);
    int*   hkey    = (int*)w;   w += HSIZE * sizeof(int);
    int*   hcnt    = (int*)w;   /* hash arrays die after k_compact; */
    int*   csr_v   = hkey;      /* CSR aliases them to save workspace */
    int*   csr_c   = hcnt;

    k_params<<<1, 64, 0, stream>>>(attn_w, edge_emb, params, stot, ecount);
    k_hash_init<<<HSIZE / 256, 256, 0, stream>>>(hkey, hcnt, deg);
    k_insert<<<(NEDGE + 255) / 256, 256, 0, stream>>>(edges, hkey, hcnt);
    k_mlp<<<N_NODES, ATTD, 0, stream>>>(X, W1, b1, W2, b2, s, stot);
    k_compact<<<HSIZE / 256, 256, 0, stream>>>(hkey, hcnt, elist_k, elist_c, deg, ecount);
    k_scan<<<1, 1024, 0, stream>>>(deg, rowptr, rowcur);
    k_scatter<<<(NEDGE + 255) / 256, 256, 0, stream>>>(elist_k, elist_c, ecount, rowcur,
                                                       csr_v, csr_c);
    k_gather<<<(N_NODES * 64) / 256, 256, 0, stream>>>(rowptr, csr_v, csr_c, s, params,
                                                       &stot[0], s2, &stot[1], 0);
    k_gather<<<(N_NODES * 64) / 256, 256, 0, stream>>>(rowptr, csr_v, csr_c, s2, params,
                                                       &stot[1], out, nullptr, 1);
}

// Round 3
// 117.102 us; speedup vs baseline: 3.0277x; 3.0277x over previous
//
#include <hip/hip_runtime.h>

#define N_NODES 6144
#define ATTD 128
#define HIDD 96
#define EPT 100000
#define NTYPE 3
#define NEDGE (NTYPE * EPT)
#define HBITS 19
#define HSIZE (1u << HBITS)
#define HMASK (HSIZE - 1)
#define NEG 0.2f

// ---- init: hash table, degrees, and (block 0) per-(l,h) params + stot zero ----
__global__ void k_init(const float* __restrict__ attn_w,
                       const float* __restrict__ edge_emb,
                       float* __restrict__ params, float* __restrict__ stot,
                       int* __restrict__ hkey, int* __restrict__ hcnt,
                       int* __restrict__ deg) {
    int i = blockIdx.x * blockDim.x + threadIdx.x;
    if (i < (int)HSIZE) { hkey[i] = -1; hcnt[i] = 0; }
    if (i <= N_NODES) deg[i] = 0;
    if (blockIdx.x == 0) {
        int t = threadIdx.x;
        if (t < 2) stot[t] = 0.f;
        if (t < 4) {
            // attn_w flat: (2,2,22,1) -> (l*2+h)*22 + j
            const float* w = attn_w + t * 22;
            float* p = params + t * 8;
            p[0] = w[0];    // w0 (src coeff)
            p[1] = w[21];   // w_last (tgt coeff)
            for (int ty = 0; ty < NTYPE; ++ty) {
                float acc = 0.f;
                for (int j = 0; j < 20; ++j) acc += edge_emb[ty * 20 + j] * w[1 + j];
                p[2 + ty] = acc;
            }
        }
    }
}

// ---- insert edges: dedupe by (src,tgt), packed per-type counts, degree on creation ----
__global__ void k_insert(const int* __restrict__ edges,
                         int* __restrict__ hkey, int* __restrict__ hcnt,
                         int* __restrict__ deg) {
    int k = blockIdx.x * blockDim.x + threadIdx.x;
    if (k >= NEDGE) return;
    int t = k / EPT;
    int e = k - t * EPT;
    int src = edges[t * (2 * EPT) + e];
    int tgt = edges[t * (2 * EPT) + EPT + e];
    int key = (src << 13) | tgt;   // both < 8192
    unsigned slot = ((unsigned)key * 2654435761u) >> (32 - HBITS);
    while (true) {
        int prev = atomicCAS(&hkey[slot], -1, key);
        if (prev == -1) { atomicAdd(&deg[src], 1); break; }  // unique-edge creation
        if (prev == key) break;
        slot = (slot + 1) & HMASK;
    }
    atomicAdd(&hcnt[slot], 1 << (10 * t));  // packed 3x10-bit type counts
}

// ---- MLP scores: s = leaky(X@W1+b1)@W2 + b2 ----
__global__ void k_mlp(const float* __restrict__ X, const float* __restrict__ W1,
                      const float* __restrict__ b1, const float* __restrict__ W2,
                      const float* __restrict__ b2, float* __restrict__ s) {
    int row = blockIdx.x;
    int tid = threadIdx.x;
    __shared__ float xs[ATTD];
    xs[tid] = X[row * ATTD + tid];
    __syncthreads();
    float val = 0.f;
    if (tid < HIDD) {
        float acc = b1[tid];
#pragma unroll
        for (int k = 0; k < ATTD; ++k) acc += xs[k] * W1[k * HIDD + tid];
        float h = acc > 0.f ? acc : NEG * acc;
        val = h * W2[tid];
    }
#pragma unroll
    for (int off = 32; off; off >>= 1) val += __shfl_down(val, off, 64);
    __shared__ float red[2];
    if ((tid & 63) == 0) red[tid >> 6] = val;
    __syncthreads();
    if (tid == 0) s[row] = red[0] + red[1] + b2[0];
}

// ---- single-block: exclusive scan of degrees -> rowptr/rowcur; also stot[0] = sum(s) ----
__global__ void k_scan(const int* __restrict__ deg, const float* __restrict__ s,
                       int* __restrict__ rowptr, int* __restrict__ rowcur,
                       float* __restrict__ stot0) {
    __shared__ int part[1024];
    int t = threadIdx.x;
    int base = t * 6;           // 6144 / 1024
    int d[6];
    int sum = 0;
    float fs = 0.f;
#pragma unroll
    for (int j = 0; j < 6; ++j) { d[j] = deg[base + j]; sum += d[j]; fs += s[base + j]; }
    part[t] = sum;
    __syncthreads();
    for (int off = 1; off < 1024; off <<= 1) {
        int v = (t >= off) ? part[t - off] : 0;
        __syncthreads();
        part[t] += v;
        __syncthreads();
    }
    int run = part[t] - sum;    // exclusive prefix of this thread
#pragma unroll
    for (int j = 0; j < 6; ++j) {
        rowptr[base + j] = run;
        rowcur[base + j] = run;
        run += d[j];
    }
    if (t == 1023) rowptr[N_NODES] = run;
    // ---- stot[0] reduction ----
#pragma unroll
    for (int off = 32; off; off >>= 1) fs += __shfl_down(fs, off, 64);
    __shared__ float fred[16];
    if ((t & 63) == 0) fred[t >> 6] = fs;
    __syncthreads();
    if (t == 0) {
        float a = 0.f;
#pragma unroll
        for (int k = 0; k < 16; ++k) a += fred[k];
        *stot0 = a;
    }
}

// ---- scatter live hash slots directly into CSR (per-row atomics only) ----
__global__ void k_scatter(const int* __restrict__ hkey, const int* __restrict__ hcnt,
                          int* __restrict__ rowcur, int2* __restrict__ csr) {
    int i = blockIdx.x * blockDim.x + threadIdx.x;
    if (i >= (int)HSIZE) return;
    int key = hkey[i];
    if (key < 0) return;
    int u = key >> 13;
    int pos = atomicAdd(&rowcur[u], 1);
    csr[pos] = make_int2(key & 8191, hcnt[i]);
}

// ---- per-layer gather: one wave per row, no atomics ----
__global__ void k_gather(const int* __restrict__ rowptr, const int2* __restrict__ csr,
                         const float* __restrict__ s, const float* __restrict__ params,
                         const float* __restrict__ stot_l, float* __restrict__ dst, int l) {
    int wid = (blockIdx.x * blockDim.x + threadIdx.x) >> 6;
    int lane = threadIdx.x & 63;
    if (wid >= N_NODES) return;
    int u = wid;
    float su = s[u];
    const float* p0 = params + (l * 2 + 0) * 8;
    const float* p1 = params + (l * 2 + 1) * 8;
    float w00 = p0[0], w01 = p0[1], e00 = p0[2], e01 = p0[3], e02 = p0[4];
    float w10 = p1[0], w11 = p1[1], e10 = p1[2], e11 = p1[3], e12 = p1[4];
    float num0 = 0.f, den0 = 0.f, num1 = 0.f, den1 = 0.f;
    int beg = rowptr[u], end = rowptr[u + 1];
    for (int i = beg + lane; i < end; i += 64) {
        int2 vc = csr[i];
        int v = vc.x;
        int cw = vc.y;
        float c0 = (float)(cw & 1023);
        float c1 = (float)((cw >> 10) & 1023);
        float c2 = (float)((cw >> 20) & 1023);
        float C = c0 + c1 + c2;
        float sv = s[v];
        float A0 = C * (w00 * su + w01 * sv) + c0 * e00 + c1 * e01 + c2 * e02;
        float la0 = A0 > 0.f ? A0 : NEG * A0;
        float g0 = expf(la0) - 1.f;
        num0 += g0 * sv; den0 += g0;
        float A1 = C * (w10 * su + w11 * sv) + c0 * e10 + c1 * e11 + c2 * e12;
        float la1 = A1 > 0.f ? A1 : NEG * A1;
        float g1 = expf(la1) - 1.f;
        num1 += g1 * sv; den1 += g1;
    }
#pragma unroll
    for (int off = 32; off; off >>= 1) {
        num0 += __shfl_down(num0, off, 64);
        den0 += __shfl_down(den0, off, 64);
        num1 += __shfl_down(num1, off, 64);
        den1 += __shfl_down(den1, off, 64);
    }
    if (lane == 0) {
        float S = *stot_l;
        float r0 = (S + num0) / ((float)N_NODES + den0);
        float r1 = (S + num1) / ((float)N_NODES + den1);
        dst[u] = 0.5f * (r0 + r1);
    }
}

// ---- single-block sum: stot[1] = sum(s2) ----
__global__ void k_sum(const float* __restrict__ v, float* __restrict__ dst) {
    int t = threadIdx.x;
    float a = 0.f;
#pragma unroll
    for (int j = 0; j < 6; ++j) a += v[t * 6 + j];
#pragma unroll
    for (int off = 32; off; off >>= 1) a += __shfl_down(a, off, 64);
    __shared__ float red[16];
    if ((t & 63) == 0) red[t >> 6] = a;
    __syncthreads();
    if (t == 0) {
        float s = 0.f;
#pragma unroll
        for (int k = 0; k < 16; ++k) s += red[k];
        *dst = s;
    }
}

extern "C" void kernel_launch(void* const* d_in, const int* in_sizes, int n_in,
                              void* d_out, int out_size, void* d_ws, size_t ws_size,
                              hipStream_t stream) {
    const float* X        = (const float*)d_in[0];
    const int*   edges    = (const int*)d_in[1];
    const float* W1       = (const float*)d_in[2];
    const float* b1       = (const float*)d_in[3];
    const float* W2       = (const float*)d_in[4];
    const float* b2       = (const float*)d_in[5];
    const float* edge_emb = (const float*)d_in[6];
    const float* attn_w   = (const float*)d_in[7];
    float* out = (float*)d_out;

    char* w = (char*)d_ws;
    float* params  = (float*)w; w += 256;
    float* stot    = (float*)w; w += 256;
    float* s       = (float*)w; w += N_NODES * sizeof(float);
    float* s2      = (float*)w; w += N_NODES * sizeof(float);
    int*   deg     = (int*)w;   w += (N_NODES + 64) * sizeof(int);
    int*   rowptr  = (int*)w;   w += (N_NODES + 64) * sizeof(int);
    int*   rowcur  = (int*)w;   w += (N_NODES + 64) * sizeof(int);
    int2*  csr     = (int2*)w;  w += NEDGE * sizeof(int2);
    int*   hkey    = (int*)w;   w += HSIZE * sizeof(int);
    int*   hcnt    = (int*)w;

    k_init<<<HSIZE / 256, 256, 0, stream>>>(attn_w, edge_emb, params, stot,
                                            hkey, hcnt, deg);
    k_insert<<<(NEDGE + 255) / 256, 256, 0, stream>>>(edges, hkey, hcnt, deg);
    k_mlp<<<N_NODES, ATTD, 0, stream>>>(X, W1, b1, W2, b2, s);
    k_scan<<<1, 1024, 0, stream>>>(deg, s, rowptr, rowcur, &stot[0]);
    k_scatter<<<HSIZE / 256, 256, 0, stream>>>(hkey, hcnt, rowcur, csr);
    k_gather<<<(N_NODES * 64) / 256, 256, 0, stream>>>(rowptr, csr, s, params,
                                                       &stot[0], s2, 0);
    k_sum<<<1, 1024, 0, stream>>>(s2, &stot[1]);
    k_gather<<<(N_NODES * 64) / 256, 256, 0, stream>>>(rowptr, csr, s2, params,
                                                       &stot[1], out, 1);
}

// Round 4
// 51.982 us; speedup vs baseline: 6.8205x; 2.2527x over previous
//
#include <hip/hip_runtime.h>

#define N_NODES 6144
#define ATTD 128
#define HIDD 96
#define EPT 100000
#define NTYPE 3
#define NEDGE (NTYPE * EPT)
#define BCAP 128                      // per-row bucket capacity (max deg ~85)
#define CPAD 16                       // row-counter padding: 16 ints = 64B line
#define NEG 0.2f
#define BUCKET_BLOCKS ((NEDGE + 255) / 256)   // 1172
#define MLP_BLOCKS (N_NODES / 2)              // 3072 (2 rows / 256-thr block)

// ---- k0: zero padded row counters, compute per-(l,h) params, zero stot ----
__global__ void k_init(const float* __restrict__ attn_w,
                       const float* __restrict__ edge_emb,
                       float* __restrict__ params, float* __restrict__ stot,
                       int* __restrict__ rcnt) {
    int i = blockIdx.x * blockDim.x + threadIdx.x;
    if (i < N_NODES * CPAD) rcnt[i] = 0;
    if (i < 2) stot[i] = 0.f;
    if (i < 4) {
        // attn_w flat: (2,2,22,1) -> (l*2+h)*22 + j
        const float* w = attn_w + i * 22;
        float* p = params + i * 8;
        p[0] = w[0];    // w0 (src coeff)
        p[1] = w[21];   // w_last (tgt coeff)
        for (int ty = 0; ty < NTYPE; ++ty) {
            float acc = 0.f;
            for (int j = 0; j < 20; ++j) acc += edge_emb[ty * 20 + j] * w[1 + j];
            p[2 + ty] = acc;
        }
    }
}

// ---- k1 (fused): bucket edges by row  |  MLP scores ----
__global__ void k_build(const int* __restrict__ edges, int* __restrict__ rcnt,
                        int* __restrict__ bucket,
                        const float* __restrict__ X, const float* __restrict__ W1,
                        const float* __restrict__ b1, const float* __restrict__ W2,
                        const float* __restrict__ b2, float* __restrict__ s) {
    int bid = blockIdx.x;
    if (bid < BUCKET_BLOCKS) {
        int k = bid * 256 + threadIdx.x;
        if (k < NEDGE) {
            int t = k / EPT;
            int e = k - t * EPT;
            int src = edges[t * (2 * EPT) + e];
            int tgt = edges[t * (2 * EPT) + EPT + e];
            int pos = atomicAdd(&rcnt[src * CPAD], 1);
            if (pos < BCAP) bucket[src * BCAP + pos] = (t << 13) | tgt;
        }
        return;
    }
    // ---- MLP: s = leaky(X@W1+b1)@W2 + b2, two rows per block ----
    int half = threadIdx.x >> 7;          // 0 or 1
    int tid  = threadIdx.x & 127;
    int row  = (bid - BUCKET_BLOCKS) * 2 + half;
    __shared__ float xs[2][ATTD];
    __shared__ float red[2][2];
    xs[half][tid] = X[row * ATTD + tid];
    __syncthreads();
    float val = 0.f;
    if (tid < HIDD) {
        float acc = b1[tid];
#pragma unroll
        for (int k = 0; k < ATTD; ++k) acc += xs[half][k] * W1[k * HIDD + tid];
        float h = acc > 0.f ? acc : NEG * acc;
        val = h * W2[tid];
    }
#pragma unroll
    for (int off = 32; off; off >>= 1) val += __shfl_down(val, off, 64);
    if ((threadIdx.x & 63) == 0) red[half][tid >> 6] = val;
    __syncthreads();
    if (tid == 0) s[row] = red[half][0] + red[half][1] + b2[0];
}

// ---- 1-block sum: dst = sum(v[0..6143]) ----
__global__ void k_sum(const float* __restrict__ v, float* __restrict__ dst) {
    int t = threadIdx.x;
    float a = 0.f;
#pragma unroll
    for (int j = 0; j < 6; ++j) a += v[t * 6 + j];
#pragma unroll
    for (int off = 32; off; off >>= 1) a += __shfl_down(a, off, 64);
    __shared__ float red[16];
    if ((t & 63) == 0) red[t >> 6] = a;
    __syncthreads();
    if (t == 0) {
        float s = 0.f;
#pragma unroll
        for (int k = 0; k < 16; ++k) s += red[k];
        *dst = s;
    }
}

// ---- k3: per-row LDS dedup + layer-0 gather; writes merged (v,cw) + cnt2 ----
__global__ void k_gather1(const int* __restrict__ rcnt, int* bucket,
                          const float* __restrict__ s, const float* __restrict__ params,
                          const float* __restrict__ stot0, float* __restrict__ s2,
                          int* __restrict__ cw2, int* __restrict__ cnt2) {
    int wid  = (blockIdx.x * blockDim.x + threadIdx.x) >> 6;
    int lane = threadIdx.x & 63;
    int wv   = threadIdx.x >> 6;
    __shared__ int hk[4 * 256];
    __shared__ int hc[4 * 256];
    int* K = hk + wv * 256;
    int* C = hc + wv * 256;
#pragma unroll
    for (int j = lane; j < 256; j += 64) { K[j] = -1; C[j] = 0; }
    __syncthreads();
    int u = wid;
    int d = rcnt[u * CPAD];
    if (d > BCAP) d = BCAP;
    for (int i = lane; i < d; i += 64) {
        int raw = bucket[u * BCAP + i];
        int v = raw & 8191;
        int t = raw >> 13;
        unsigned slot = ((unsigned)v * 2654435761u) >> 24;  // 8-bit slot
        while (true) {
            int prev = atomicCAS(&K[slot], -1, v);
            if (prev == -1 || prev == v) break;
            slot = (slot + 1) & 255;
        }
        atomicAdd(&C[slot], 1 << (10 * t));
    }
    __syncthreads();
    const float* p0 = params + 0;
    const float* p1 = params + 8;
    float su = s[u];
    float w00 = p0[0], w01 = p0[1], e00 = p0[2], e01 = p0[3], e02 = p0[4];
    float w10 = p1[0], w11 = p1[1], e10 = p1[2], e11 = p1[3], e12 = p1[4];
    float num0 = 0.f, den0 = 0.f, num1 = 0.f, den1 = 0.f;
    int base = 0;
#pragma unroll
    for (int it = 0; it < 4; ++it) {
        int j = it * 64 + lane;
        int key = K[j];
        bool live = key >= 0;
        unsigned long long m = __ballot(live);
        if (live) {
            int cw = C[j];
            int idx = base + __popcll(m & ((1ull << lane) - 1ull));
            bucket[u * BCAP + idx] = key;      // raw row already consumed
            cw2[u * BCAP + idx] = cw;
            float c0 = (float)(cw & 1023);
            float c1 = (float)((cw >> 10) & 1023);
            float c2 = (float)((cw >> 20) & 1023);
            float Cc = c0 + c1 + c2;
            float sv = s[key];
            float A0 = Cc * (w00 * su + w01 * sv) + c0 * e00 + c1 * e01 + c2 * e02;
            float la0 = A0 > 0.f ? A0 : NEG * A0;
            float g0 = expf(la0) - 1.f;
            num0 += g0 * sv; den0 += g0;
            float A1 = Cc * (w10 * su + w11 * sv) + c0 * e10 + c1 * e11 + c2 * e12;
            float la1 = A1 > 0.f ? A1 : NEG * A1;
            float g1 = expf(la1) - 1.f;
            num1 += g1 * sv; den1 += g1;
        }
        base += __popcll(m);
    }
#pragma unroll
    for (int off = 32; off; off >>= 1) {
        num0 += __shfl_down(num0, off, 64);
        den0 += __shfl_down(den0, off, 64);
        num1 += __shfl_down(num1, off, 64);
        den1 += __shfl_down(den1, off, 64);
    }
    if (lane == 0) {
        cnt2[u] = base;
        float S = *stot0;
        float r0 = (S + num0) / ((float)N_NODES + den0);
        float r1 = (S + num1) / ((float)N_NODES + den1);
        s2[u] = 0.5f * (r0 + r1);
    }
}

// ---- k5: layer-1 gather over merged lists ----
__global__ void k_gather2(const int* __restrict__ cnt2, const int* __restrict__ bucket,
                          const int* __restrict__ cw2, const float* __restrict__ s,
                          const float* __restrict__ params, const float* __restrict__ stot1,
                          float* __restrict__ dst) {
    int wid  = (blockIdx.x * blockDim.x + threadIdx.x) >> 6;
    int lane = threadIdx.x & 63;
    int u = wid;
    float su = s[u];
    const float* p0 = params + 16;
    const float* p1 = params + 24;
    float w00 = p0[0], w01 = p0[1], e00 = p0[2], e01 = p0[3], e02 = p0[4];
    float w10 = p1[0], w11 = p1[1], e10 = p1[2], e11 = p1[3], e12 = p1[4];
    float num0 = 0.f, den0 = 0.f, num1 = 0.f, den1 = 0.f;
    int d = cnt2[u];
    for (int i = lane; i < d; i += 64) {
        int v  = bucket[u * BCAP + i];
        int cw = cw2[u * BCAP + i];
        float c0 = (float)(cw & 1023);
        float c1 = (float)((cw >> 10) & 1023);
        float c2 = (float)((cw >> 20) & 1023);
        float Cc = c0 + c1 + c2;
        float sv = s[v];
        float A0 = Cc * (w00 * su + w01 * sv) + c0 * e00 + c1 * e01 + c2 * e02;
        float la0 = A0 > 0.f ? A0 : NEG * A0;
        float g0 = expf(la0) - 1.f;
        num0 += g0 * sv; den0 += g0;
        float A1 = Cc * (w10 * su + w11 * sv) + c0 * e10 + c1 * e11 + c2 * e12;
        float la1 = A1 > 0.f ? A1 : NEG * A1;
        float g1 = expf(la1) - 1.f;
        num1 += g1 * sv; den1 += g1;
    }
#pragma unroll
    for (int off = 32; off; off >>= 1) {
        num0 += __shfl_down(num0, off, 64);
        den0 += __shfl_down(den0, off, 64);
        num1 += __shfl_down(num1, off, 64);
        den1 += __shfl_down(den1, off, 64);
    }
    if (lane == 0) {
        float S = *stot1;
        float r0 = (S + num0) / ((float)N_NODES + den0);
        float r1 = (S + num1) / ((float)N_NODES + den1);
        dst[u] = 0.5f * (r0 + r1);
    }
}

extern "C" void kernel_launch(void* const* d_in, const int* in_sizes, int n_in,
                              void* d_out, int out_size, void* d_ws, size_t ws_size,
                              hipStream_t stream) {
    const float* X        = (const float*)d_in[0];
    const int*   edges    = (const int*)d_in[1];
    const float* W1       = (const float*)d_in[2];
    const float* b1       = (const float*)d_in[3];
    const float* W2       = (const float*)d_in[4];
    const float* b2       = (const float*)d_in[5];
    const float* edge_emb = (const float*)d_in[6];
    const float* attn_w   = (const float*)d_in[7];
    float* out = (float*)d_out;

    char* w = (char*)d_ws;
    float* params = (float*)w; w += 256;
    float* stot   = (float*)w; w += 256;
    float* s      = (float*)w; w += N_NODES * sizeof(float);
    float* s2     = (float*)w; w += N_NODES * sizeof(float);
    int*   cnt2   = (int*)w;   w += N_NODES * sizeof(int);
    int*   rcnt   = (int*)w;   w += N_NODES * CPAD * sizeof(int);
    int*   bucket = (int*)w;   w += N_NODES * BCAP * sizeof(int);
    int*   cw2    = (int*)w;   w += N_NODES * BCAP * sizeof(int);

    k_init<<<(N_NODES * CPAD) / 256, 256, 0, stream>>>(attn_w, edge_emb, params,
                                                       stot, rcnt);
    k_build<<<BUCKET_BLOCKS + MLP_BLOCKS, 256, 0, stream>>>(edges, rcnt, bucket,
                                                            X, W1, b1, W2, b2, s);
    k_sum<<<1, 1024, 0, stream>>>(s, &stot[0]);
    k_gather1<<<(N_NODES * 64) / 256, 256, 0, stream>>>(rcnt, bucket, s, params,
                                                        &stot[0], s2, cw2, cnt2);
    k_sum<<<1, 1024, 0, stream>>>(s2, &stot[1]);
    k_gather2<<<(N_NODES * 64) / 256, 256, 0, stream>>>(cnt2, bucket, cw2, s2, params,
                                                        &stot[1], out);
}

// Round 5
// 50.357 us; speedup vs baseline: 7.0406x; 1.0323x over previous
//
#include <hip/hip_runtime.h>

#define N_NODES 6144
#define ATTD 128
#define HIDD 96
#define EPT 100000
#define NTYPE 3
#define NEDGE (NTYPE * EPT)
#define BCAP 128                      // per-row bucket capacity (max deg ~85)
#define CPAD 16                       // row-counter padding: 16 ints = 64B line
#define PSTRIDE 16                    // partial-cell padding: 16 floats = 64B line
#define NCELL 64                      // partial accumulator cells
#define NEG 0.2f
#define BUCKET_BLOCKS ((NEDGE + 255) / 256)   // 1172
#define MLP_BLOCKS (N_NODES / 2)              // 3072 (2 rows / 256-thr block)

// ---- k0: zero row counters + partial cells, compute per-(l,h) params ----
__global__ void k_init(const float* __restrict__ attn_w,
                       const float* __restrict__ edge_emb,
                       float* __restrict__ params, int* __restrict__ rcnt,
                       float* __restrict__ part0, float* __restrict__ part1) {
    int i = blockIdx.x * blockDim.x + threadIdx.x;
    if (i < N_NODES * CPAD) rcnt[i] = 0;
    if (i < NCELL * PSTRIDE) { part0[i] = 0.f; part1[i] = 0.f; }
    if (i < 4) {
        // attn_w flat: (2,2,22,1) -> (l*2+h)*22 + j
        const float* w = attn_w + i * 22;
        float* p = params + i * 8;
        p[0] = w[0];    // w0 (src coeff)
        p[1] = w[21];   // w_last (tgt coeff)
        for (int ty = 0; ty < NTYPE; ++ty) {
            float acc = 0.f;
            for (int j = 0; j < 20; ++j) acc += edge_emb[ty * 20 + j] * w[1 + j];
            p[2 + ty] = acc;
        }
    }
}

// ---- k1 (fused): bucket edges by row  |  MLP scores + stot0 partials ----
__global__ void k_build(const int* __restrict__ edges, int* __restrict__ rcnt,
                        int* __restrict__ bucket,
                        const float* __restrict__ X, const float* __restrict__ W1,
                        const float* __restrict__ b1, const float* __restrict__ W2,
                        const float* __restrict__ b2, float* __restrict__ s,
                        float* __restrict__ part0) {
    int bid = blockIdx.x;
    if (bid < BUCKET_BLOCKS) {
        int k = bid * 256 + threadIdx.x;
        if (k < NEDGE) {
            int t = k / EPT;
            int e = k - t * EPT;
            int src = edges[t * (2 * EPT) + e];
            int tgt = edges[t * (2 * EPT) + EPT + e];
            int pos = atomicAdd(&rcnt[src * CPAD], 1);
            if (pos < BCAP) bucket[src * BCAP + pos] = (t << 13) | tgt;
        }
        return;
    }
    // ---- MLP: s = leaky(X@W1+b1)@W2 + b2, two rows per block ----
    int half = threadIdx.x >> 7;          // 0 or 1
    int tid  = threadIdx.x & 127;
    int row  = (bid - BUCKET_BLOCKS) * 2 + half;
    __shared__ float xs[2][ATTD];
    __shared__ float red[2][2];
    __shared__ float sred[2];
    xs[half][tid] = X[row * ATTD + tid];
    __syncthreads();
    float val = 0.f;
    if (tid < HIDD) {
        float acc = b1[tid];
#pragma unroll
        for (int k = 0; k < ATTD; ++k) acc += xs[half][k] * W1[k * HIDD + tid];
        float h = acc > 0.f ? acc : NEG * acc;
        val = h * W2[tid];
    }
#pragma unroll
    for (int off = 32; off; off >>= 1) val += __shfl_down(val, off, 64);
    if ((threadIdx.x & 63) == 0) red[half][tid >> 6] = val;
    __syncthreads();
    if (tid == 0) {
        float r = red[half][0] + red[half][1] + b2[0];
        s[row] = r;
        sred[half] = r;
    }
    __syncthreads();
    if (threadIdx.x == 0)
        atomicAdd(&part0[((bid - BUCKET_BLOCKS) & (NCELL - 1)) * PSTRIDE],
                  sred[0] + sred[1]);
}

// ---- k2: per-row LDS dedup + layer-0 gather; merged lists + stot1 partials ----
__global__ void k_gather1(const int* __restrict__ rcnt, int* bucket,
                          const float* __restrict__ s, const float* __restrict__ params,
                          const float* __restrict__ part0, float* __restrict__ s2,
                          int* __restrict__ cw2, int* __restrict__ cnt2,
                          float* __restrict__ part1) {
    int lane = threadIdx.x & 63;
    int wv   = threadIdx.x >> 6;
    int u    = blockIdx.x * 4 + wv;
    __shared__ int hk[4 * 256];
    __shared__ int hc[4 * 256];
    __shared__ float stot_s;
    __shared__ float wsum[4];
    int* K = hk + wv * 256;
    int* C = hc + wv * 256;
#pragma unroll
    for (int j = lane; j < 256; j += 64) { K[j] = -1; C[j] = 0; }
    if (wv == 0) {
        float v = part0[lane * PSTRIDE];
#pragma unroll
        for (int off = 32; off; off >>= 1) v += __shfl_down(v, off, 64);
        if (lane == 0) stot_s = v;
    }
    __syncthreads();
    int d = rcnt[u * CPAD];
    if (d > BCAP) d = BCAP;
    for (int i = lane; i < d; i += 64) {
        int raw = bucket[u * BCAP + i];
        int v = raw & 8191;
        int t = raw >> 13;
        unsigned slot = ((unsigned)v * 2654435761u) >> 24;  // 8-bit slot
        while (true) {
            int prev = atomicCAS(&K[slot], -1, v);
            if (prev == -1 || prev == v) break;
            slot = (slot + 1) & 255;
        }
        atomicAdd(&C[slot], 1 << (10 * t));
    }
    __syncthreads();
    const float* p0 = params + 0;
    const float* p1 = params + 8;
    float su = s[u];
    float w00 = p0[0], w01 = p0[1], e00 = p0[2], e01 = p0[3], e02 = p0[4];
    float w10 = p1[0], w11 = p1[1], e10 = p1[2], e11 = p1[3], e12 = p1[4];
    float num0 = 0.f, den0 = 0.f, num1 = 0.f, den1 = 0.f;
    int base = 0;
#pragma unroll
    for (int it = 0; it < 4; ++it) {
        int j = it * 64 + lane;
        int key = K[j];
        bool live = key >= 0;
        unsigned long long m = __ballot(live);
        if (live) {
            int cw = C[j];
            int idx = base + __popcll(m & ((1ull << lane) - 1ull));
            bucket[u * BCAP + idx] = key;      // raw row already consumed
            cw2[u * BCAP + idx] = cw;
            float c0 = (float)(cw & 1023);
            float c1 = (float)((cw >> 10) & 1023);
            float c2 = (float)((cw >> 20) & 1023);
            float Cc = c0 + c1 + c2;
            float sv = s[key];
            float A0 = Cc * (w00 * su + w01 * sv) + c0 * e00 + c1 * e01 + c2 * e02;
            float la0 = A0 > 0.f ? A0 : NEG * A0;
            float g0 = expf(la0) - 1.f;
            num0 += g0 * sv; den0 += g0;
            float A1 = Cc * (w10 * su + w11 * sv) + c0 * e10 + c1 * e11 + c2 * e12;
            float la1 = A1 > 0.f ? A1 : NEG * A1;
            float g1 = expf(la1) - 1.f;
            num1 += g1 * sv; den1 += g1;
        }
        base += __popcll(m);
    }
#pragma unroll
    for (int off = 32; off; off >>= 1) {
        num0 += __shfl_down(num0, off, 64);
        den0 += __shfl_down(den0, off, 64);
        num1 += __shfl_down(num1, off, 64);
        den1 += __shfl_down(den1, off, 64);
    }
    if (lane == 0) {
        cnt2[u] = base;
        float S = stot_s;
        float r0 = (S + num0) / ((float)N_NODES + den0);
        float r1 = (S + num1) / ((float)N_NODES + den1);
        float val = 0.5f * (r0 + r1);
        s2[u] = val;
        wsum[wv] = val;
    }
    __syncthreads();
    if (threadIdx.x == 0)
        atomicAdd(&part1[(blockIdx.x & (NCELL - 1)) * PSTRIDE],
                  wsum[0] + wsum[1] + wsum[2] + wsum[3]);
}

// ---- k3: layer-1 gather over merged lists ----
__global__ void k_gather2(const int* __restrict__ cnt2, const int* __restrict__ bucket,
                          const int* __restrict__ cw2, const float* __restrict__ s,
                          const float* __restrict__ params, const float* __restrict__ part1,
                          float* __restrict__ dst) {
    int lane = threadIdx.x & 63;
    int wv   = threadIdx.x >> 6;
    int u    = blockIdx.x * 4 + wv;
    __shared__ float stot_s;
    if (wv == 0) {
        float v = part1[lane * PSTRIDE];
#pragma unroll
        for (int off = 32; off; off >>= 1) v += __shfl_down(v, off, 64);
        if (lane == 0) stot_s = v;
    }
    __syncthreads();
    float su = s[u];
    const float* p0 = params + 16;
    const float* p1 = params + 24;
    float w00 = p0[0], w01 = p0[1], e00 = p0[2], e01 = p0[3], e02 = p0[4];
    float w10 = p1[0], w11 = p1[1], e10 = p1[2], e11 = p1[3], e12 = p1[4];
    float num0 = 0.f, den0 = 0.f, num1 = 0.f, den1 = 0.f;
    int d = cnt2[u];
    for (int i = lane; i < d; i += 64) {
        int v  = bucket[u * BCAP + i];
        int cw = cw2[u * BCAP + i];
        float c0 = (float)(cw & 1023);
        float c1 = (float)((cw >> 10) & 1023);
        float c2 = (float)((cw >> 20) & 1023);
        float Cc = c0 + c1 + c2;
        float sv = s[v];
        float A0 = Cc * (w00 * su + w01 * sv) + c0 * e00 + c1 * e01 + c2 * e02;
        float la0 = A0 > 0.f ? A0 : NEG * A0;
        float g0 = expf(la0) - 1.f;
        num0 += g0 * sv; den0 += g0;
        float A1 = Cc * (w10 * su + w11 * sv) + c0 * e10 + c1 * e11 + c2 * e12;
        float la1 = A1 > 0.f ? A1 : NEG * A1;
        float g1 = expf(la1) - 1.f;
        num1 += g1 * sv; den1 += g1;
    }
#pragma unroll
    for (int off = 32; off; off >>= 1) {
        num0 += __shfl_down(num0, off, 64);
        den0 += __shfl_down(den0, off, 64);
        num1 += __shfl_down(num1, off, 64);
        den1 += __shfl_down(den1, off, 64);
    }
    if (lane == 0) {
        float S = stot_s;
        float r0 = (S + num0) / ((float)N_NODES + den0);
        float r1 = (S + num1) / ((float)N_NODES + den1);
        dst[u] = 0.5f * (r0 + r1);
    }
}

extern "C" void kernel_launch(void* const* d_in, const int* in_sizes, int n_in,
                              void* d_out, int out_size, void* d_ws, size_t ws_size,
                              hipStream_t stream) {
    const float* X        = (const float*)d_in[0];
    const int*   edges    = (const int*)d_in[1];
    const float* W1       = (const float*)d_in[2];
    const float* b1       = (const float*)d_in[3];
    const float* W2       = (const float*)d_in[4];
    const float* b2       = (const float*)d_in[5];
    const float* edge_emb = (const float*)d_in[6];
    const float* attn_w   = (const float*)d_in[7];
    float* out = (float*)d_out;

    char* w = (char*)d_ws;
    float* params = (float*)w; w += 256;
    float* part0  = (float*)w; w += NCELL * PSTRIDE * sizeof(float);
    float* part1  = (float*)w; w += NCELL * PSTRIDE * sizeof(float);
    float* s      = (float*)w; w += N_NODES * sizeof(float);
    float* s2     = (float*)w; w += N_NODES * sizeof(float);
    int*   cnt2   = (int*)w;   w += N_NODES * sizeof(int);
    int*   rcnt   = (int*)w;   w += N_NODES * CPAD * sizeof(int);
    int*   bucket = (int*)w;   w += N_NODES * BCAP * sizeof(int);
    int*   cw2    = (int*)w;   w += N_NODES * BCAP * sizeof(int);

    k_init<<<(N_NODES * CPAD) / 256, 256, 0, stream>>>(attn_w, edge_emb, params,
                                                       rcnt, part0, part1);
    k_build<<<BUCKET_BLOCKS + MLP_BLOCKS, 256, 0, stream>>>(edges, rcnt, bucket,
                                                            X, W1, b1, W2, b2, s, part0);
    k_gather1<<<N_NODES / 4, 256, 0, stream>>>(rcnt, bucket, s, params, part0,
                                               s2, cw2, cnt2, part1);
    k_gather2<<<N_NODES / 4, 256, 0, stream>>>(cnt2, bucket, cw2, s2, params, part1,
                                               out);
}